// Round 15
// baseline (457.830 us; speedup 1.0000x reference)
//
#include <hip/hip_runtime.h>

typedef float __attribute__((ext_vector_type(4))) f32x4;
typedef unsigned int __attribute__((ext_vector_type(2))) u32x2;
typedef int __attribute__((ext_vector_type(4))) i32x4;
typedef int __attribute__((ext_vector_type(8))) i32x8;

#define M_DIM 65536
#define N_DIM 1024
#define K_DIM 1024

#define BM 64            // rows per panel; block processes 4 consecutive panels

#define WS_NEEDED ((size_t)K_DIM * N_DIM)   // W8 only: 1 MB
#define SCALE_ONE 0x7F7F7F7F                // e8m0 127 = 2^0 -> scale 1.0

// pack 4 floats -> 4 fp8 e4m3 bytes (RNE, OCP on gfx950)
__device__ inline unsigned int cvt4(float f0, float f1, float f2, float f3) {
    int r = __builtin_amdgcn_cvt_pk_fp8_f32(f0, f1, 0, false);
    r = __builtin_amdgcn_cvt_pk_fp8_f32(f2, f3, r, true);
    return (unsigned int)r;
}

// ---------------- pass 1: W f32 -> fp8 packed [K/16][N][16] ----------------
// out[(t*N + n)*16 + s] = fp8(W[t*16 + s][n])
__global__ __launch_bounds__(256) void quant_w_kernel(const float* __restrict__ w,
                                                      unsigned char* __restrict__ out) {
    const int idx = blockIdx.x * 256 + threadIdx.x;  // 0..65535
    const int t = idx >> 10, n = idx & 1023;
    const float* wp = w + (size_t)(t * 16) * N_DIM + n;
    unsigned int r[4];
#pragma unroll
    for (int q = 0; q < 4; ++q) {
        float f0 = wp[(size_t)(q * 4 + 0) * N_DIM];
        float f1 = wp[(size_t)(q * 4 + 1) * N_DIM];
        float f2 = wp[(size_t)(q * 4 + 2) * N_DIM];
        float f3 = wp[(size_t)(q * 4 + 3) * N_DIM];
        r[q] = cvt4(f0, f1, f2, f3);
    }
    i32x4 v; v.x = (int)r[0]; v.y = (int)r[1]; v.z = (int)r[2]; v.w = (int)r[3];
    ((i32x4*)out)[idx] = v;
}

// ---------------- pass 2: fused quantize+GEMM, 4 panels/block, dbuf pipeline ----------------
// Each block: 4 panels of 64 rows x full N. Per panel: 4 chunks of 256 cols; wave = all
// 64 rows x 32 cols (no B duplication; B traffic 1 GB L2 total). While computing panel p,
// panel p+1 is staged: group-g loads issue at chunk-g start (f32x4 regs), cvt+ds_write
// after chunk-g compute (compiler vmcnt via reg deps). __syncthreads only at panel ends.
__global__ __launch_bounds__(512) void gemm_fused2_kernel(const float* __restrict__ A,
                                                          const unsigned char* __restrict__ B8,
                                                          const float* __restrict__ scale_b,
                                                          float* __restrict__ out) {
    __shared__ __attribute__((aligned(16))) unsigned char sA[2][BM * K_DIM];  // 2 x 64 KB

    const int tid = threadIdx.x;
    const int l = tid & 63;
    const int wid = tid >> 6;        // 0..7 -> col group (32 cols within chunk)
    const int lr = l & 15;
    const int lg = l >> 4;           // k-quarter

    // stage unit u = tid + j*512 (j 0..31): row = u>>8 (0..63), kq = u&255 (f32x4 idx)
    // LDS byte = row*1024 + ((k>>4)^(row&7))*16 + (k&15), k = kq*4  (4B store)
#define STAGE_LOAD(PBASE, G, REGS)                                                      \
    _Pragma("unroll") for (int i = 0; i < 8; ++i) {                                     \
        const int u = tid + ((G) * 8 + i) * 512;                                        \
        REGS[i] = *(const f32x4*)((PBASE) + (size_t)(u >> 8) * K_DIM + (u & 255) * 4);  \
    }
#define STAGE_WRITE(BUF, G, REGS)                                                       \
    _Pragma("unroll") for (int i = 0; i < 8; ++i) {                                     \
        const int u = tid + ((G) * 8 + i) * 512;                                        \
        const int row = u >> 8;                                                         \
        const int k = (u & 255) * 4;                                                    \
        const unsigned int wv = cvt4(REGS[i][0], REGS[i][1], REGS[i][2], REGS[i][3]);   \
        *(unsigned int*)(sA[BUF] + row * 1024 + (((k >> 4) ^ (row & 7)) << 4) + (k & 15)) = wv; \
    }

    // ---- prologue: stage panel 0 into buf 0 ----
    {
        const float* p0 = A + (size_t)(blockIdx.x * 4) * BM * K_DIM;
        f32x4 rg[8];
#pragma unroll
        for (int g = 0; g < 4; ++g) {
            STAGE_LOAD(p0, g, rg);
            STAGE_WRITE(0, g, rg);
        }
    }
    __syncthreads();

    for (int p = 0; p < 4; ++p) {
        const int cur = p & 1;
        const int m0 = (blockIdx.x * 4 + p) * BM;
        const float* pnext = A + (size_t)(m0 + BM) * K_DIM;
        const bool more = (p < 3);

#pragma unroll
        for (int ch = 0; ch < 4; ++ch) {
            f32x4 rg[8];
            if (more) STAGE_LOAD(pnext, ch, rg);   // issue early; HBM hides under compute

            const int nb = ch * 256 + wid * 32;
            f32x4 acc[4][2];
#pragma unroll
            for (int i = 0; i < 4; ++i)
#pragma unroll
                for (int j = 0; j < 2; ++j) acc[i][j] = (f32x4)0.0f;

#pragma unroll
            for (int t = 0; t < 8; ++t) {
                i32x8 bf[2];
#pragma unroll
                for (int nj = 0; nj < 2; ++nj) {
                    const int n = nb + nj * 16 + lr;
                    const int kt16 = t * 8 + lg * 2;
                    const i32x4 b0 = *(const i32x4*)(B8 + ((size_t)kt16 * N_DIM + n) * 16);
                    const i32x4 b1 = *(const i32x4*)(B8 + ((size_t)(kt16 + 1) * N_DIM + n) * 16);
                    bf[nj] = __builtin_shufflevector(b0, b1, 0, 1, 2, 3, 4, 5, 6, 7);
                }
#pragma unroll
                for (int mi = 0; mi < 4; ++mi) {
                    const int row = mi * 16 + lr;
                    const i32x4 a0 = *(const i32x4*)(sA[cur] + row * 1024 +
                                                     (t * 8 + ((2 * lg + 0) ^ (row & 7))) * 16);
                    const i32x4 a1 = *(const i32x4*)(sA[cur] + row * 1024 +
                                                     (t * 8 + ((2 * lg + 1) ^ (row & 7))) * 16);
                    const i32x8 af = __builtin_shufflevector(a0, a1, 0, 1, 2, 3, 4, 5, 6, 7);
#pragma unroll
                    for (int nj = 0; nj < 2; ++nj)
                        acc[mi][nj] = __builtin_amdgcn_mfma_scale_f32_16x16x128_f8f6f4(
                            af, bf[nj], acc[mi][nj], 0, 0,   // cbsz=fp8, blgp=fp8
                            0, SCALE_ONE, 0, SCALE_ONE);
                }
            }

            // ---- store chunk: C/D layout col = lane&15, row = (lane>>4)*4 + reg ----
#pragma unroll
            for (int nj = 0; nj < 2; ++nj) {
                const int col = nb + nj * 16 + lr;
                const float sc = scale_b[col];
#pragma unroll
                for (int mi = 0; mi < 4; ++mi) {
                    const int row = m0 + mi * 16 + lg * 4;
#pragma unroll
                    for (int r = 0; r < 4; ++r) {
                        const float v = acc[mi][nj][r] * sc;
                        out[(size_t)(row + r) * N_DIM + col] = (float)(_Float16)v;
                    }
                }
            }

            if (more) STAGE_WRITE(cur ^ 1, ch, rg);  // write late into the other buffer
        }
        __syncthreads();   // panel boundary: publish buf[cur^1], release buf[cur]
    }
#undef STAGE_LOAD
#undef STAGE_WRITE
}

// ---------------- fallback: round-6 fused kernel (passing, 350 us) ----------------
__global__ __launch_bounds__(256) void gemm_fused_kernel(const float* __restrict__ A,
                                                         const float* __restrict__ W,
                                                         const float* __restrict__ scale_b,
                                                         float* __restrict__ out) {
    __shared__ __attribute__((aligned(16))) unsigned char sA[128 * 64];
    __shared__ __attribute__((aligned(16))) unsigned char sB[64 * 128];

    const int tid = threadIdx.x;
    const int l = tid & 63;
    const int wid = tid >> 6;
    const int lr = l & 15;
    const int lg = l >> 4;
    const int wr = wid >> 1;
    const int wc = wid & 1;
    const int n0 = blockIdx.x * 128;
    const int m0 = blockIdx.y * 128;

    f32x4 acc[4][4];
#pragma unroll
    for (int i = 0; i < 4; ++i)
#pragma unroll
        for (int j = 0; j < 4; ++j) acc[i][j] = (f32x4)0.0f;

    const int a_g = tid & 7;
    const int a_rb = tid >> 3;
    const int aswz = lr & 6;

    for (int kt = 0; kt < K_DIM / 64; ++kt) {
        const int k0 = kt * 64;
#pragma unroll
        for (int o = 0; o < 4; ++o) {
            const int row = o * 32 + a_rb;
            const float* ap = A + (size_t)(m0 + row) * K_DIM + k0 + a_g * 8;
            const f32x4 v0 = *(const f32x4*)ap;
            const f32x4 v1 = *(const f32x4*)(ap + 4);
            u32x2 r;
            r.x = cvt4(v0[0], v0[1], v0[2], v0[3]);
            r.y = cvt4(v1[0], v1[1], v1[2], v1[3]);
            *(u32x2*)(sA + row * 64 + ((a_g ^ (row & 6)) * 8)) = r;
        }
#pragma unroll
        for (int o = 0; o < 4; ++o) {
            const int e = o * 256 + tid;
            const int g = e >> 7;
            const int n = e & 127;
            const float* wp = W + (size_t)(k0 + g * 8) * N_DIM + n0 + n;
            float f[8];
#pragma unroll
            for (int j = 0; j < 8; ++j) f[j] = wp[(size_t)j * N_DIM];
            u32x2 r;
            r.x = cvt4(f[0], f[1], f[2], f[3]);
            r.y = cvt4(f[4], f[5], f[6], f[7]);
            *(u32x2*)(sB + g * 1024 + n * 8) = r;
        }
        __syncthreads();

#pragma unroll
        for (int kk = 0; kk < 2; ++kk) {
            long long af[4], bfr[4];
            const int gread = kk * 4 + lg;
#pragma unroll
            for (int mi = 0; mi < 4; ++mi) {
                const int m = wr * 64 + mi * 16 + lr;
                af[mi] = *(const long long*)(sA + m * 64 + ((gread ^ aswz) * 8));
            }
#pragma unroll
            for (int nj = 0; nj < 4; ++nj) {
                const int n = wc * 64 + nj * 16 + lr;
                bfr[nj] = *(const long long*)(sB + gread * 1024 + n * 8);
            }
#pragma unroll
            for (int mi = 0; mi < 4; ++mi)
#pragma unroll
                for (int nj = 0; nj < 4; ++nj)
                    acc[mi][nj] = __builtin_amdgcn_mfma_f32_16x16x32_fp8_fp8(
                        af[mi], bfr[nj], acc[mi][nj], 0, 0, 0);
        }
        __syncthreads();
    }

#pragma unroll
    for (int nj = 0; nj < 4; ++nj) {
        const int col = n0 + wc * 64 + nj * 16 + lr;
        const float sc = scale_b[col];
#pragma unroll
        for (int mi = 0; mi < 4; ++mi) {
            const int row = m0 + wr * 64 + mi * 16 + lg * 4;
#pragma unroll
            for (int r = 0; r < 4; ++r) {
                const float v = acc[mi][nj][r] * sc;
                out[(size_t)(row + r) * N_DIM + col] = (float)(_Float16)v;
            }
        }
    }
}

extern "C" void kernel_launch(void* const* d_in, const int* in_sizes, int n_in,
                              void* d_out, int out_size, void* d_ws, size_t ws_size,
                              hipStream_t stream) {
    (void)out_size;
    const void* pA = d_in[0];
    const void* pW = (n_in > 1) ? d_in[1] : d_in[0];
    const void* pS = (n_in > 2) ? d_in[2] : d_in[0];
    for (int i = 0; i < n_in && i < 3; ++i) {
        if (in_sizes[i] == M_DIM * K_DIM) pA = d_in[i];
        else if (in_sizes[i] == K_DIM * N_DIM) pW = d_in[i];
        else if (in_sizes[i] == N_DIM) pS = d_in[i];
    }
    const float* A = (const float*)pA;
    const float* W = (const float*)pW;
    const float* sb = (const float*)pS;
    float* out = (float*)d_out;

    if (ws_size >= WS_NEEDED && d_ws != nullptr) {
        unsigned char* W8 = (unsigned char*)d_ws;
        quant_w_kernel<<<256, 256, 0, stream>>>(W, W8);
        gemm_fused2_kernel<<<M_DIM / (BM * 4), 512, 0, stream>>>(A, W8, sb, out);
    } else {
        gemm_fused_kernel<<<dim3(N_DIM / 128, M_DIM / 128), 256, 0, stream>>>(A, W, sb, out);
    }
}

// Round 16
// 383.564 us; speedup vs baseline: 1.1936x; 1.1936x over previous
//
#include <hip/hip_runtime.h>

typedef float __attribute__((ext_vector_type(4))) f32x4;
typedef unsigned int __attribute__((ext_vector_type(2))) u32x2;
typedef int __attribute__((ext_vector_type(4))) i32x4;
typedef int __attribute__((ext_vector_type(8))) i32x8;

#define M_DIM 65536
#define N_DIM 1024
#define K_DIM 1024

#define BM 64            // rows per block; block covers full N via 4 chunks of 256

#define WS_NEEDED ((size_t)K_DIM * N_DIM)   // W8 only: 1 MB
#define SCALE_ONE 0x7F7F7F7F                // e8m0 127 = 2^0 -> scale 1.0

// pack 4 floats -> 4 fp8 e4m3 bytes (RNE, OCP on gfx950)
__device__ inline unsigned int cvt4(float f0, float f1, float f2, float f3) {
    int r = __builtin_amdgcn_cvt_pk_fp8_f32(f0, f1, 0, false);
    r = __builtin_amdgcn_cvt_pk_fp8_f32(f2, f3, r, true);
    return (unsigned int)r;
}

// ---------------- pass 1: W f32 -> fp8 packed [K/16][N][16] ----------------
// out[(t*N + n)*16 + s] = fp8(W[t*16 + s][n])
__global__ __launch_bounds__(256) void quant_w_kernel(const float* __restrict__ w,
                                                      unsigned char* __restrict__ out) {
    const int idx = blockIdx.x * 256 + threadIdx.x;  // 0..65535
    const int t = idx >> 10, n = idx & 1023;
    const float* wp = w + (size_t)(t * 16) * N_DIM + n;
    unsigned int r[4];
#pragma unroll
    for (int q = 0; q < 4; ++q) {
        float f0 = wp[(size_t)(q * 4 + 0) * N_DIM];
        float f1 = wp[(size_t)(q * 4 + 1) * N_DIM];
        float f2 = wp[(size_t)(q * 4 + 2) * N_DIM];
        float f3 = wp[(size_t)(q * 4 + 3) * N_DIM];
        r[q] = cvt4(f0, f1, f2, f3);
    }
    i32x4 v; v.x = (int)r[0]; v.y = (int)r[1]; v.z = (int)r[2]; v.w = (int)r[3];
    ((i32x4*)out)[idx] = v;
}

// ---------------- pass 2: fused quantize+GEMM, 64 rows x full N per block ----------------
// Round-14 structure (proven best) with 1x8 wave layout:
// Stage: A f32 (64x1024, read ONCE from HBM) -> fp8 RNE -> LDS 64KB, XOR(row&7) 16B-unit
// swizzle. ONE __syncthreads. Then 4 chunks of 256 cols: each of the 8 waves owns ALL
// 64 rows x 32 cols (no B duplication; 8 MFMA per 4 bf L2-loads). No further barriers.
__global__ __launch_bounds__(512) void gemm_fused2_kernel(const float* __restrict__ A,
                                                          const unsigned char* __restrict__ B8,
                                                          const float* __restrict__ scale_b,
                                                          float* __restrict__ out) {
    __shared__ __attribute__((aligned(16))) unsigned char sA[BM * K_DIM];  // 64 KB

    const int tid = threadIdx.x;
    const int l = tid & 63;
    const int wid = tid >> 6;        // 0..7 -> 32-col group within the 256-col chunk
    const int lr = l & 15;
    const int lg = l >> 4;           // k-quarter
    const int m0 = blockIdx.x * BM;

    // ---- stage + quantize A (once): 16384 f32x4 units, unit u = tid + j*512 ----
    // row = u>>8, kq = u&255 (f32x4 index), k = kq*4. Lane-consecutive u => coalesced.
    // LDS byte = row*1024 + ((k>>4)^(row&7))*16 + (k&15); b32 writes, 2-way banks (free).
#pragma unroll
    for (int j = 0; j < 32; ++j) {
        const int u = tid + j * 512;
        const int row = u >> 8;
        const int kq = u & 255;
        const f32x4 v = *(const f32x4*)(A + (size_t)(m0 + row) * K_DIM + kq * 4);
        const unsigned int w = cvt4(v[0], v[1], v[2], v[3]);
        const int k = kq * 4;
        *(unsigned int*)(sA + row * 1024 + (((k >> 4) ^ (row & 7)) << 4) + (k & 15)) = w;
    }
    __syncthreads();   // only barrier: sA is read-only afterwards

    for (int ch = 0; ch < 4; ++ch) {           // 256-col chunk; this wave: cols nb..nb+31
        const int nb = ch * 256 + wid * 32;
        f32x4 acc[4][2];
#pragma unroll
        for (int i = 0; i < 4; ++i)
#pragma unroll
            for (int j = 0; j < 2; ++j) acc[i][j] = (f32x4)0.0f;

#pragma unroll
        for (int t = 0; t < 8; ++t) {          // K-tile of 128
            i32x8 bf[2];
#pragma unroll
            for (int nj = 0; nj < 2; ++nj) {
                const int n = nb + nj * 16 + lr;
                const int kt16 = t * 8 + lg * 2;
                const i32x4 b0 = *(const i32x4*)(B8 + ((size_t)kt16 * N_DIM + n) * 16);
                const i32x4 b1 = *(const i32x4*)(B8 + ((size_t)(kt16 + 1) * N_DIM + n) * 16);
                bf[nj] = __builtin_shufflevector(b0, b1, 0, 1, 2, 3, 4, 5, 6, 7);
            }
#pragma unroll
            for (int mi = 0; mi < 4; ++mi) {   // all 64 rows
                const int row = mi * 16 + lr;
                const i32x4 a0 = *(const i32x4*)(sA + row * 1024 +
                                                 (t * 8 + ((2 * lg + 0) ^ (row & 7))) * 16);
                const i32x4 a1 = *(const i32x4*)(sA + row * 1024 +
                                                 (t * 8 + ((2 * lg + 1) ^ (row & 7))) * 16);
                const i32x8 af = __builtin_shufflevector(a0, a1, 0, 1, 2, 3, 4, 5, 6, 7);
#pragma unroll
                for (int nj = 0; nj < 2; ++nj)
                    acc[mi][nj] = __builtin_amdgcn_mfma_scale_f32_16x16x128_f8f6f4(
                        af, bf[nj], acc[mi][nj], 0, 0,   // cbsz=fp8, blgp=fp8
                        0, SCALE_ONE, 0, SCALE_ONE);
            }
        }

        // ---- store chunk: C/D layout col = lane&15, row = (lane>>4)*4 + reg ----
        // Per wave, nj=0..1 covers 32 contiguous cols = one full 128B line per row.
#pragma unroll
        for (int nj = 0; nj < 2; ++nj) {
            const int col = nb + nj * 16 + lr;
            const float sc = scale_b[col];
#pragma unroll
            for (int mi = 0; mi < 4; ++mi) {
                const int row = m0 + mi * 16 + lg * 4;
#pragma unroll
                for (int r = 0; r < 4; ++r) {
                    const float v = acc[mi][nj][r] * sc;
                    out[(size_t)(row + r) * N_DIM + col] = (float)(_Float16)v;
                }
            }
        }
    }
}

// ---------------- fallback: round-6 fused kernel (passing, 350 us) ----------------
__global__ __launch_bounds__(256) void gemm_fused_kernel(const float* __restrict__ A,
                                                         const float* __restrict__ W,
                                                         const float* __restrict__ scale_b,
                                                         float* __restrict__ out) {
    __shared__ __attribute__((aligned(16))) unsigned char sA[128 * 64];
    __shared__ __attribute__((aligned(16))) unsigned char sB[64 * 128];

    const int tid = threadIdx.x;
    const int l = tid & 63;
    const int wid = tid >> 6;
    const int lr = l & 15;
    const int lg = l >> 4;
    const int wr = wid >> 1;
    const int wc = wid & 1;
    const int n0 = blockIdx.x * 128;
    const int m0 = blockIdx.y * 128;

    f32x4 acc[4][4];
#pragma unroll
    for (int i = 0; i < 4; ++i)
#pragma unroll
        for (int j = 0; j < 4; ++j) acc[i][j] = (f32x4)0.0f;

    const int a_g = tid & 7;
    const int a_rb = tid >> 3;
    const int aswz = lr & 6;

    for (int kt = 0; kt < K_DIM / 64; ++kt) {
        const int k0 = kt * 64;
#pragma unroll
        for (int o = 0; o < 4; ++o) {
            const int row = o * 32 + a_rb;
            const float* ap = A + (size_t)(m0 + row) * K_DIM + k0 + a_g * 8;
            const f32x4 v0 = *(const f32x4*)ap;
            const f32x4 v1 = *(const f32x4*)(ap + 4);
            u32x2 r;
            r.x = cvt4(v0[0], v0[1], v0[2], v0[3]);
            r.y = cvt4(v1[0], v1[1], v1[2], v1[3]);
            *(u32x2*)(sA + row * 64 + ((a_g ^ (row & 6)) * 8)) = r;
        }
#pragma unroll
        for (int o = 0; o < 4; ++o) {
            const int e = o * 256 + tid;
            const int g = e >> 7;
            const int n = e & 127;
            const float* wp = W + (size_t)(k0 + g * 8) * N_DIM + n0 + n;
            float f[8];
#pragma unroll
            for (int j = 0; j < 8; ++j) f[j] = wp[(size_t)j * N_DIM];
            u32x2 r;
            r.x = cvt4(f[0], f[1], f[2], f[3]);
            r.y = cvt4(f[4], f[5], f[6], f[7]);
            *(u32x2*)(sB + g * 1024 + n * 8) = r;
        }
        __syncthreads();

#pragma unroll
        for (int kk = 0; kk < 2; ++kk) {
            long long af[4], bfr[4];
            const int gread = kk * 4 + lg;
#pragma unroll
            for (int mi = 0; mi < 4; ++mi) {
                const int m = wr * 64 + mi * 16 + lr;
                af[mi] = *(const long long*)(sA + m * 64 + ((gread ^ aswz) * 8));
            }
#pragma unroll
            for (int nj = 0; nj < 4; ++nj) {
                const int n = wc * 64 + nj * 16 + lr;
                bfr[nj] = *(const long long*)(sB + gread * 1024 + n * 8);
            }
#pragma unroll
            for (int mi = 0; mi < 4; ++mi)
#pragma unroll
                for (int nj = 0; nj < 4; ++nj)
                    acc[mi][nj] = __builtin_amdgcn_mfma_f32_16x16x32_fp8_fp8(
                        af[mi], bfr[nj], acc[mi][nj], 0, 0, 0);
        }
        __syncthreads();
    }

#pragma unroll
    for (int nj = 0; nj < 4; ++nj) {
        const int col = n0 + wc * 64 + nj * 16 + lr;
        const float sc = scale_b[col];
#pragma unroll
        for (int mi = 0; mi < 4; ++mi) {
            const int row = m0 + wr * 64 + mi * 16 + lg * 4;
#pragma unroll
            for (int r = 0; r < 4; ++r) {
                const float v = acc[mi][nj][r] * sc;
                out[(size_t)(row + r) * N_DIM + col] = (float)(_Float16)v;
            }
        }
    }
}

extern "C" void kernel_launch(void* const* d_in, const int* in_sizes, int n_in,
                              void* d_out, int out_size, void* d_ws, size_t ws_size,
                              hipStream_t stream) {
    (void)out_size;
    const void* pA = d_in[0];
    const void* pW = (n_in > 1) ? d_in[1] : d_in[0];
    const void* pS = (n_in > 2) ? d_in[2] : d_in[0];
    for (int i = 0; i < n_in && i < 3; ++i) {
        if (in_sizes[i] == M_DIM * K_DIM) pA = d_in[i];
        else if (in_sizes[i] == K_DIM * N_DIM) pW = d_in[i];
        else if (in_sizes[i] == N_DIM) pS = d_in[i];
    }
    const float* A = (const float*)pA;
    const float* W = (const float*)pW;
    const float* sb = (const float*)pS;
    float* out = (float*)d_out;

    if (ws_size >= WS_NEEDED && d_ws != nullptr) {
        unsigned char* W8 = (unsigned char*)d_ws;
        quant_w_kernel<<<256, 256, 0, stream>>>(W, W8);
        gemm_fused2_kernel<<<M_DIM / BM, 512, 0, stream>>>(A, W8, sb, out);
    } else {
        gemm_fused_kernel<<<dim3(N_DIM / 128, M_DIM / 128), 256, 0, stream>>>(A, W, sb, out);
    }
}

// Round 17
// 158.551 us; speedup vs baseline: 2.8876x; 2.4192x over previous
//
#include <hip/hip_runtime.h>

typedef float __attribute__((ext_vector_type(4))) f32x4;
typedef unsigned int __attribute__((ext_vector_type(2))) u32x2;
typedef int __attribute__((ext_vector_type(4))) i32x4;
typedef int __attribute__((ext_vector_type(8))) i32x8;

#define M_DIM 65536
#define N_DIM 1024
#define K_DIM 1024

#define BM 64            // rows per block; block covers full N via 8 chunks of 128

#define WS_NEEDED ((size_t)K_DIM * N_DIM)   // W8 only: 1 MB
#define SCALE_ONE 0x7F7F7F7F                // e8m0 127 = 2^0 -> scale 1.0

// pack 4 floats -> 4 fp8 e4m3 bytes (RNE, OCP on gfx950)
__device__ inline unsigned int cvt4(float f0, float f1, float f2, float f3) {
    int r = __builtin_amdgcn_cvt_pk_fp8_f32(f0, f1, 0, false);
    r = __builtin_amdgcn_cvt_pk_fp8_f32(f2, f3, r, true);
    return (unsigned int)r;
}

// ---------------- pass 1: W f32 -> fp8 packed [K/16][N][16] ----------------
// out[(t*N + n)*16 + s] = fp8(W[t*16 + s][n])
__global__ __launch_bounds__(256) void quant_w_kernel(const float* __restrict__ w,
                                                      unsigned char* __restrict__ out) {
    const int idx = blockIdx.x * 256 + threadIdx.x;  // 0..65535
    const int t = idx >> 10, n = idx & 1023;
    const float* wp = w + (size_t)(t * 16) * N_DIM + n;
    unsigned int r[4];
#pragma unroll
    for (int q = 0; q < 4; ++q) {
        float f0 = wp[(size_t)(q * 4 + 0) * N_DIM];
        float f1 = wp[(size_t)(q * 4 + 1) * N_DIM];
        float f2 = wp[(size_t)(q * 4 + 2) * N_DIM];
        float f3 = wp[(size_t)(q * 4 + 3) * N_DIM];
        r[q] = cvt4(f0, f1, f2, f3);
    }
    i32x4 v; v.x = (int)r[0]; v.y = (int)r[1]; v.z = (int)r[2]; v.w = (int)r[3];
    ((i32x4*)out)[idx] = v;
}

// ---------------- pass 2: fused quantize+GEMM, 64 rows x full N per block ----------------
// Round-14 structure (proven best, 178us total), 2x4 wave layout, 8 chunks of 128 cols.
// Stage: A f32 (64x1024, read ONCE from HBM) -> fp8 RNE -> LDS 64KB, XOR(row&7) 16B-unit
// swizzle. ONE __syncthreads. Then per chunk: af from LDS, bf direct from L2-resident W8,
// 16x16x128 MX-MFMA (scale=1.0), NON-TEMPORAL f32 stores (no L2 write-allocate pollution).
__global__ __launch_bounds__(512) void gemm_fused2_kernel(const float* __restrict__ A,
                                                          const unsigned char* __restrict__ B8,
                                                          const float* __restrict__ scale_b,
                                                          float* __restrict__ out) {
    __shared__ __attribute__((aligned(16))) unsigned char sA[BM * K_DIM];  // 64 KB

    const int tid = threadIdx.x;
    const int l = tid & 63;
    const int wid = tid >> 6;        // 0..7
    const int lr = l & 15;
    const int lg = l >> 4;           // k-quarter
    const int wr2 = wid >> 2;        // 0..1: row half (32 rows)
    const int wc2 = wid & 3;         // 0..3: col quarter within chunk (32 cols)
    const int m0 = blockIdx.x * BM;

    // ---- stage + quantize A (once): 16384 f32x4 units, unit u = tid + j*512 ----
    // row = u>>8, kq = u&255 (f32x4 index), k = kq*4. Lane-consecutive u => coalesced.
    // LDS byte = row*1024 + ((k>>4)^(row&7))*16 + (k&15); b32 writes, 2-way banks (free).
#pragma unroll
    for (int j = 0; j < 32; ++j) {
        const int u = tid + j * 512;
        const int row = u >> 8;
        const int kq = u & 255;
        const f32x4 v = *(const f32x4*)(A + (size_t)(m0 + row) * K_DIM + kq * 4);
        const unsigned int w = cvt4(v[0], v[1], v[2], v[3]);
        const int k = kq * 4;
        *(unsigned int*)(sA + row * 1024 + (((k >> 4) ^ (row & 7)) << 4) + (k & 15)) = w;
    }
    __syncthreads();   // only barrier: sA is read-only afterwards

    for (int ch = 0; ch < 8; ++ch) {           // 128-col chunk
        const int nb = ch * 128;
        f32x4 acc[2][2];
#pragma unroll
        for (int i = 0; i < 2; ++i)
#pragma unroll
            for (int j = 0; j < 2; ++j) acc[i][j] = (f32x4)0.0f;

#pragma unroll
        for (int t = 0; t < 8; ++t) {          // K-tile of 128
            i32x8 af[2], bf[2];
#pragma unroll
            for (int mi = 0; mi < 2; ++mi) {
                const int row = wr2 * 32 + mi * 16 + lr;
                const i32x4 a0 = *(const i32x4*)(sA + row * 1024 +
                                                 (t * 8 + ((2 * lg + 0) ^ (row & 7))) * 16);
                const i32x4 a1 = *(const i32x4*)(sA + row * 1024 +
                                                 (t * 8 + ((2 * lg + 1) ^ (row & 7))) * 16);
                af[mi] = __builtin_shufflevector(a0, a1, 0, 1, 2, 3, 4, 5, 6, 7);
            }
#pragma unroll
            for (int nj = 0; nj < 2; ++nj) {
                const int n = nb + wc2 * 32 + nj * 16 + lr;
                const int kt16 = t * 8 + lg * 2;
                const i32x4 b0 = *(const i32x4*)(B8 + ((size_t)kt16 * N_DIM + n) * 16);
                const i32x4 b1 = *(const i32x4*)(B8 + ((size_t)(kt16 + 1) * N_DIM + n) * 16);
                bf[nj] = __builtin_shufflevector(b0, b1, 0, 1, 2, 3, 4, 5, 6, 7);
            }
#pragma unroll
            for (int mi = 0; mi < 2; ++mi)
#pragma unroll
                for (int nj = 0; nj < 2; ++nj)
                    acc[mi][nj] = __builtin_amdgcn_mfma_scale_f32_16x16x128_f8f6f4(
                        af[mi], bf[nj], acc[mi][nj], 0, 0,   // cbsz=fp8, blgp=fp8
                        0, SCALE_ONE, 0, SCALE_ONE);
        }

        // ---- store chunk: C/D layout col = lane&15, row = (lane>>4)*4 + reg ----
        // Non-temporal: output is write-once, never re-read -> keep it out of L2.
#pragma unroll
        for (int nj = 0; nj < 2; ++nj) {
            const int col = nb + wc2 * 32 + nj * 16 + lr;
            const float sc = scale_b[col];
#pragma unroll
            for (int mi = 0; mi < 2; ++mi) {
                const int row = m0 + wr2 * 32 + mi * 16 + lg * 4;
#pragma unroll
                for (int r = 0; r < 4; ++r) {
                    const float v = acc[mi][nj][r] * sc;
                    __builtin_nontemporal_store((float)(_Float16)v,
                                                &out[(size_t)(row + r) * N_DIM + col]);
                }
            }
        }
    }
}

// ---------------- fallback: round-6 fused kernel (passing, 350 us) ----------------
__global__ __launch_bounds__(256) void gemm_fused_kernel(const float* __restrict__ A,
                                                         const float* __restrict__ W,
                                                         const float* __restrict__ scale_b,
                                                         float* __restrict__ out) {
    __shared__ __attribute__((aligned(16))) unsigned char sA[128 * 64];
    __shared__ __attribute__((aligned(16))) unsigned char sB[64 * 128];

    const int tid = threadIdx.x;
    const int l = tid & 63;
    const int wid = tid >> 6;
    const int lr = l & 15;
    const int lg = l >> 4;
    const int wr = wid >> 1;
    const int wc = wid & 1;
    const int n0 = blockIdx.x * 128;
    const int m0 = blockIdx.y * 128;

    f32x4 acc[4][4];
#pragma unroll
    for (int i = 0; i < 4; ++i)
#pragma unroll
        for (int j = 0; j < 4; ++j) acc[i][j] = (f32x4)0.0f;

    const int a_g = tid & 7;
    const int a_rb = tid >> 3;
    const int aswz = lr & 6;

    for (int kt = 0; kt < K_DIM / 64; ++kt) {
        const int k0 = kt * 64;
#pragma unroll
        for (int o = 0; o < 4; ++o) {
            const int row = o * 32 + a_rb;
            const float* ap = A + (size_t)(m0 + row) * K_DIM + k0 + a_g * 8;
            const f32x4 v0 = *(const f32x4*)ap;
            const f32x4 v1 = *(const f32x4*)(ap + 4);
            u32x2 r;
            r.x = cvt4(v0[0], v0[1], v0[2], v0[3]);
            r.y = cvt4(v1[4 - 4], v1[1], v1[2], v1[3]);  // v1[0..3]
            *(u32x2*)(sA + row * 64 + ((a_g ^ (row & 6)) * 8)) = r;
        }
#pragma unroll
        for (int o = 0; o < 4; ++o) {
            const int e = o * 256 + tid;
            const int g = e >> 7;
            const int n = e & 127;
            const float* wp = W + (size_t)(k0 + g * 8) * N_DIM + n0 + n;
            float f[8];
#pragma unroll
            for (int j = 0; j < 8; ++j) f[j] = wp[(size_t)j * N_DIM];
            u32x2 r;
            r.x = cvt4(f[0], f[1], f[2], f[3]);
            r.y = cvt4(f[4], f[5], f[6], f[7]);
            *(u32x2*)(sB + g * 1024 + n * 8) = r;
        }
        __syncthreads();

#pragma unroll
        for (int kk = 0; kk < 2; ++kk) {
            long long af[4], bfr[4];
            const int gread = kk * 4 + lg;
#pragma unroll
            for (int mi = 0; mi < 4; ++mi) {
                const int m = wr * 64 + mi * 16 + lr;
                af[mi] = *(const long long*)(sA + m * 64 + ((gread ^ aswz) * 8));
            }
#pragma unroll
            for (int nj = 0; nj < 4; ++nj) {
                const int n = wc * 64 + nj * 16 + lr;
                bfr[nj] = *(const long long*)(sB + gread * 1024 + n * 8);
            }
#pragma unroll
            for (int mi = 0; mi < 4; ++mi)
#pragma unroll
                for (int nj = 0; nj < 4; ++nj)
                    acc[mi][nj] = __builtin_amdgcn_mfma_f32_16x16x32_fp8_fp8(
                        af[mi], bfr[nj], acc[mi][nj], 0, 0, 0);
        }
        __syncthreads();
    }

#pragma unroll
    for (int nj = 0; nj < 4; ++nj) {
        const int col = n0 + wc * 64 + nj * 16 + lr;
        const float sc = scale_b[col];
#pragma unroll
        for (int mi = 0; mi < 4; ++mi) {
            const int row = m0 + wr * 64 + mi * 16 + lg * 4;
#pragma unroll
            for (int r = 0; r < 4; ++r) {
                const float v = acc[mi][nj][r] * sc;
                out[(size_t)(row + r) * N_DIM + col] = (float)(_Float16)v;
            }
        }
    }
}

extern "C" void kernel_launch(void* const* d_in, const int* in_sizes, int n_in,
                              void* d_out, int out_size, void* d_ws, size_t ws_size,
                              hipStream_t stream) {
    (void)out_size;
    const void* pA = d_in[0];
    const void* pW = (n_in > 1) ? d_in[1] : d_in[0];
    const void* pS = (n_in > 2) ? d_in[2] : d_in[0];
    for (int i = 0; i < n_in && i < 3; ++i) {
        if (in_sizes[i] == M_DIM * K_DIM) pA = d_in[i];
        else if (in_sizes[i] == K_DIM * N_DIM) pW = d_in[i];
        else if (in_sizes[i] == N_DIM) pS = d_in[i];
    }
    const float* A = (const float*)pA;
    const float* W = (const float*)pW;
    const float* sb = (const float*)pS;
    float* out = (float*)d_out;

    if (ws_size >= WS_NEEDED && d_ws != nullptr) {
        unsigned char* W8 = (unsigned char*)d_ws;
        quant_w_kernel<<<256, 256, 0, stream>>>(W, W8);
        gemm_fused2_kernel<<<M_DIM / BM, 512, 0, stream>>>(A, W8, sb, out);
    } else {
        gemm_fused_kernel<<<dim3(N_DIM / 128, M_DIM / 128), 256, 0, stream>>>(A, W, sb, out);
    }
}